// Round 1
// baseline (725.507 us; speedup 1.0000x reference)
//
#include <hip/hip_runtime.h>

#define NFEAT 256
#define GS 32
#define NG 8
#define BATCH 32
#define HW 4096
#define NTOT (BATCH*HW)   // 131072 samples per channel
#define EPSV 1e-5f

// ws layout (float offsets)
#define RPART_SZ (NG*64*1024)                 // 524288 floats
#define SPART_OFF (RPART_SZ)                  // 8*64*32 = 16384
#define WMT_OFF   (SPART_OFF + NG*64*32)      // 8*1024
#define BETA_OFF  (WMT_OFF + NG*1024)         // 8*32

// ---------------------------------------------------------------------------
// Kernel 1: per-(g,b,half) partial raw gram R = X X^T and channel sums S.
// 512 blocks x 256 threads. Thread = (row-block rb of 4 rows, lane-group l).
// Each thread: 16 iters x (4 own-row float4 + 32 col float4 loads + 512 FMA).
// Shuffle-reduce across the 32 lane-groups (half-wave), write partials to ws.
// ---------------------------------------------------------------------------
__global__ __launch_bounds__(256, 2) void dbn_stats(const float* __restrict__ x,
                                                    float* __restrict__ Rpart,
                                                    float* __restrict__ Spart) {
    int bx = blockIdx.x;            // 0..511
    int g  = bx >> 6;
    int pb = bx & 63;               // b*2 + h
    int b  = pb >> 1, h = pb & 1;
    int tid = threadIdx.x;
    int rb = tid >> 5, l = tid & 31;

    const float* xg = x + ((size_t)(b*NFEAT + g*GS))*HW + h*2048;

    float acc[4][32];
    float srow[4];
    #pragma unroll
    for (int r = 0; r < 4; ++r) {
        srow[r] = 0.f;
        #pragma unroll
        for (int d = 0; d < 32; ++d) acc[r][d] = 0.f;
    }

    #pragma unroll 1
    for (int it = 0; it < 16; ++it) {
        int p = (it*32 + l)*4;
        const float* xp = xg + p;
        float4 a[4];
        #pragma unroll
        for (int r = 0; r < 4; ++r)
            a[r] = *(const float4*)(xp + (size_t)(rb*4 + r)*HW);
        #pragma unroll 8
        for (int d = 0; d < 32; ++d) {
            float4 v = *(const float4*)(xp + (size_t)d*HW);
            #pragma unroll
            for (int r = 0; r < 4; ++r) {
                float t = acc[r][d];
                t = fmaf(a[r].x, v.x, t);
                t = fmaf(a[r].y, v.y, t);
                t = fmaf(a[r].z, v.z, t);
                t = fmaf(a[r].w, v.w, t);
                acc[r][d] = t;
            }
        }
        #pragma unroll
        for (int r = 0; r < 4; ++r)
            srow[r] += a[r].x + a[r].y + a[r].z + a[r].w;
    }

    // reduce across the 32 lane-groups (masks 1..16 stay within half-wave)
    #pragma unroll
    for (int r = 0; r < 4; ++r) {
        #pragma unroll
        for (int d = 0; d < 32; ++d) {
            float v = acc[r][d];
            v += __shfl_xor(v, 1);  v += __shfl_xor(v, 2);
            v += __shfl_xor(v, 4);  v += __shfl_xor(v, 8);
            v += __shfl_xor(v, 16);
            acc[r][d] = v;
        }
        float sv = srow[r];
        sv += __shfl_xor(sv, 1);  sv += __shfl_xor(sv, 2);
        sv += __shfl_xor(sv, 4);  sv += __shfl_xor(sv, 8);
        sv += __shfl_xor(sv, 16);
        srow[r] = sv;
    }

    if (l == 0) {
        float* Rp = Rpart + (size_t)(g*64 + pb)*1024;
        #pragma unroll
        for (int r = 0; r < 4; ++r) {
            int c = rb*4 + r;
            #pragma unroll
            for (int d = 0; d < 32; ++d) Rp[c*32 + d] = acc[r][d];
            Spart[(size_t)(g*64 + pb)*32 + c] = srow[r];
        }
    }
}

// ---------------------------------------------------------------------------
// Kernel 2: per-group solver. Reduce partials, build sigma = R - S S^T/N + eps I,
// Newton-Schulz inverse sqrt (8 iters), fold weight/bias/mean into wmT/beta.
// 8 blocks x 256 threads; each thread owns 4 matrix entries.
// ---------------------------------------------------------------------------
__global__ void dbn_solver(const float* __restrict__ Rpart, const float* __restrict__ Spart,
                           const float* __restrict__ weight, const float* __restrict__ bias,
                           float* __restrict__ wmT, float* __restrict__ beta) {
    __shared__ float Y[1024], Z[1024], T[1024], S[32], M[32], sh_s;
    int g = blockIdx.x;
    int tid = threadIdx.x;

    if (tid < 32) {
        float s = 0.f;
        for (int pb = 0; pb < 64; ++pb) s += Spart[(size_t)(g*64 + pb)*32 + tid];
        S[tid] = s;
        M[tid] = s / (float)NTOT;
    }
    float rsum[4];
    #pragma unroll
    for (int i = 0; i < 4; ++i) {
        int e = tid + 256*i;
        float s = 0.f;
        for (int pb = 0; pb < 64; ++pb) s += Rpart[(size_t)(g*64 + pb)*1024 + e];
        rsum[i] = s;
    }
    __syncthreads();

    const float invN = 1.0f/(float)NTOT;
    #pragma unroll
    for (int i = 0; i < 4; ++i) {
        int e = tid + 256*i;
        int c = e >> 5, d = e & 31;
        float v = rsum[i] - S[c]*S[d]*invN;
        if (c == d) v += EPSV;
        T[e] = v;
    }
    __syncthreads();

    if (tid == 0) {
        float tr = 0.f;
        for (int c = 0; c < 32; ++c) tr += T[c*33];
        sh_s = tr / 32.0f;
    }
    __syncthreads();
    float sc = sh_s;
    float invs = 1.0f / sc;

    #pragma unroll
    for (int i = 0; i < 4; ++i) {
        int e = tid + 256*i;
        int c = e >> 5, d = e & 31;
        Y[e] = T[e] * invs;
        Z[e] = (c == d) ? 1.0f : 0.0f;
    }
    __syncthreads();

    for (int it = 0; it < 8; ++it) {
        float a[4];
        #pragma unroll
        for (int i = 0; i < 4; ++i) {
            int e = tid + 256*i;
            int c = e >> 5, d = e & 31;
            float s = 0.f;
            for (int k = 0; k < 32; ++k) s = fmaf(Z[c*32 + k], Y[k*32 + d], s);
            a[i] = ((c == d) ? 3.0f : 0.0f) - s;
        }
        __syncthreads();
        #pragma unroll
        for (int i = 0; i < 4; ++i) T[tid + 256*i] = a[i];
        __syncthreads();
        float yn[4], zn[4];
        #pragma unroll
        for (int i = 0; i < 4; ++i) {
            int e = tid + 256*i;
            int c = e >> 5, d = e & 31;
            float sy = 0.f, sz = 0.f;
            for (int k = 0; k < 32; ++k) {
                sy = fmaf(Y[c*32 + k], T[k*32 + d], sy);
                sz = fmaf(T[c*32 + k], Z[k*32 + d], sz);
            }
            yn[i] = 0.5f*sy; zn[i] = 0.5f*sz;
        }
        __syncthreads();
        #pragma unroll
        for (int i = 0; i < 4; ++i) { int e = tid + 256*i; Y[e] = yn[i]; Z[e] = zn[i]; }
        __syncthreads();
    }

    float wfac = rsqrtf(sc);   // sigma^{-1/2} = Z / sqrt(s)
    #pragma unroll
    for (int i = 0; i < 4; ++i) {
        int e = tid + 256*i;
        int c = e >> 5, d = e & 31;
        float wc = weight[g*GS + c];
        wmT[(size_t)g*1024 + d*32 + c] = Z[e]*wfac*wc;   // transposed + weight-folded
    }
    if (tid < 32) {
        int c = tid;
        float s = 0.f;
        for (int d = 0; d < 32; ++d) s = fmaf(Z[c*32 + d], M[d], s);
        beta[g*GS + c] = -s*wfac*weight[g*GS + c] + bias[g*GS + c];
    }
}

// ---------------------------------------------------------------------------
// Kernel 3: whiten. out[c] = sum_d wmT[d][c] * x[d] + beta[c].
// One thread per spatial position; wm/beta indices are wave-uniform -> s_load,
// inner loop is pure v_fmac(v, s, v). Memory-bound: 134 MB in + 134 MB out.
// ---------------------------------------------------------------------------
__global__ __launch_bounds__(256) void dbn_whiten(const float* __restrict__ x,
                                                  const float* __restrict__ wmT,
                                                  const float* __restrict__ beta,
                                                  float* __restrict__ out) {
    int bx = blockIdx.x;            // 0..4095
    int gb = bx >> 4;               // 0..255
    int chunk = bx & 15;
    int b = gb >> 3, g = gb & 7;
    size_t base = ((size_t)(b*NFEAT + g*GS))*HW + chunk*256 + threadIdx.x;
    const float* wg = wmT + (size_t)g*1024;
    const float* bg = beta + (size_t)g*GS;

    float v[32];
    #pragma unroll
    for (int d = 0; d < 32; ++d) v[d] = x[base + (size_t)d*HW];

    float acc[32];
    #pragma unroll
    for (int c = 0; c < 32; ++c) acc[c] = bg[c];

    #pragma unroll
    for (int d = 0; d < 32; ++d) {
        float vd = v[d];
        #pragma unroll
        for (int c = 0; c < 32; ++c) acc[c] = fmaf(wg[d*32 + c], vd, acc[c]);
    }

    #pragma unroll
    for (int c = 0; c < 32; ++c) out[base + (size_t)c*HW] = acc[c];
}

extern "C" void kernel_launch(void* const* d_in, const int* in_sizes, int n_in,
                              void* d_out, int out_size, void* d_ws, size_t ws_size,
                              hipStream_t stream) {
    const float* x      = (const float*)d_in[0];
    const float* weight = (const float*)d_in[1];
    const float* bias   = (const float*)d_in[2];
    float* out = (float*)d_out;
    float* ws  = (float*)d_ws;

    float* Rpart = ws;
    float* Spart = ws + SPART_OFF;
    float* wmT   = ws + WMT_OFF;
    float* beta  = ws + BETA_OFF;

    dbn_stats <<<512, 256, 0, stream>>>(x, Rpart, Spart);
    dbn_solver<<<NG, 256, 0, stream>>>(Rpart, Spart, weight, bias, wmT, beta);
    dbn_whiten<<<4096, 256, 0, stream>>>(x, wmT, beta, out);
}

// Round 2
// 476.832 us; speedup vs baseline: 1.5215x; 1.5215x over previous
//
#include <hip/hip_runtime.h>

#define NFEAT 256
#define GS 32
#define NG 8
#define BATCH 32
#define HW 4096
#define NTOT (BATCH*HW)   // 131072 samples per channel
#define EPSV 1e-5f

// ws layout (float offsets)
#define RPART_SZ (NG*64*1024)                 // 524288 floats
#define SPART_OFF (RPART_SZ)                  // 8*64*32 = 16384
#define WMT_OFF   (SPART_OFF + NG*64*32)      // 8*1024
#define BETA_OFF  (WMT_OFF + NG*1024)         // 8*32

// ---------------------------------------------------------------------------
// Kernel 1: per-(g,b,half) partial raw gram R = X X^T and channel sums S.
// 512 blocks x 256 threads. Thread = (row-block rb: 4 rows, lane-group l).
// d-loop is FULLY unrolled (constant indices) so acc[4][32] stays in VGPRs.
// R1 fix: partial unroll made acc dynamically indexed -> scratch spill
// (VGPR=48, WRITE_SIZE=1.17GB, 490us). Two unrolled halves of 16 bound the
// load-hoisting window; __launch_bounds__(256,2) gives 256-VGPR budget.
// ---------------------------------------------------------------------------
__global__ __launch_bounds__(256, 2) void dbn_stats(const float* __restrict__ x,
                                                    float* __restrict__ Rpart,
                                                    float* __restrict__ Spart) {
    int bx = blockIdx.x;            // 0..511
    int g  = bx >> 6;
    int pb = bx & 63;               // b*2 + h
    int b  = pb >> 1, h = pb & 1;
    int tid = threadIdx.x;
    int rb = tid >> 5, l = tid & 31;

    const float* xg = x + ((size_t)(b*NFEAT + g*GS))*HW + h*2048;

    float acc[4][32];
    float srow[4];
    #pragma unroll
    for (int r = 0; r < 4; ++r) {
        srow[r] = 0.f;
        #pragma unroll
        for (int d = 0; d < 32; ++d) acc[r][d] = 0.f;
    }

    #pragma unroll 1
    for (int it = 0; it < 16; ++it) {
        int p = (it*32 + l)*4;
        const float* xp = xg + p;
        float4 a[4];
        #pragma unroll
        for (int r = 0; r < 4; ++r)
            a[r] = *(const float4*)(xp + (size_t)(rb*4 + r)*HW);

        // first half: d = 0..15, fully unrolled
        #pragma unroll
        for (int d = 0; d < 16; ++d) {
            float4 v = *(const float4*)(xp + (size_t)d*HW);
            #pragma unroll
            for (int r = 0; r < 4; ++r) {
                float t = acc[r][d];
                t = fmaf(a[r].x, v.x, t);
                t = fmaf(a[r].y, v.y, t);
                t = fmaf(a[r].z, v.z, t);
                t = fmaf(a[r].w, v.w, t);
                acc[r][d] = t;
            }
        }
        // second half: d = 16..31, fully unrolled
        #pragma unroll
        for (int d = 16; d < 32; ++d) {
            float4 v = *(const float4*)(xp + (size_t)d*HW);
            #pragma unroll
            for (int r = 0; r < 4; ++r) {
                float t = acc[r][d];
                t = fmaf(a[r].x, v.x, t);
                t = fmaf(a[r].y, v.y, t);
                t = fmaf(a[r].z, v.z, t);
                t = fmaf(a[r].w, v.w, t);
                acc[r][d] = t;
            }
        }
        #pragma unroll
        for (int r = 0; r < 4; ++r)
            srow[r] += a[r].x + a[r].y + a[r].z + a[r].w;
    }

    // reduce across the 32 lane-groups (masks 1..16 stay within half-wave)
    #pragma unroll
    for (int r = 0; r < 4; ++r) {
        #pragma unroll
        for (int d = 0; d < 32; ++d) {
            float v = acc[r][d];
            v += __shfl_xor(v, 1);  v += __shfl_xor(v, 2);
            v += __shfl_xor(v, 4);  v += __shfl_xor(v, 8);
            v += __shfl_xor(v, 16);
            acc[r][d] = v;
        }
        float sv = srow[r];
        sv += __shfl_xor(sv, 1);  sv += __shfl_xor(sv, 2);
        sv += __shfl_xor(sv, 4);  sv += __shfl_xor(sv, 8);
        sv += __shfl_xor(sv, 16);
        srow[r] = sv;
    }

    if (l == 0) {
        float* Rp = Rpart + (size_t)(g*64 + pb)*1024;
        #pragma unroll
        for (int r = 0; r < 4; ++r) {
            int c = rb*4 + r;
            #pragma unroll
            for (int d = 0; d < 32; ++d) Rp[c*32 + d] = acc[r][d];
            Spart[(size_t)(g*64 + pb)*32 + c] = srow[r];
        }
    }
}

// ---------------------------------------------------------------------------
// Kernel 2: per-group solver. Reduce partials, build sigma = R - S S^T/N + eps I,
// Newton-Schulz inverse sqrt (8 iters), fold weight/bias/mean into wmT/beta.
// 8 blocks x 256 threads; each thread owns 4 matrix entries.
// ---------------------------------------------------------------------------
__global__ void dbn_solver(const float* __restrict__ Rpart, const float* __restrict__ Spart,
                           const float* __restrict__ weight, const float* __restrict__ bias,
                           float* __restrict__ wmT, float* __restrict__ beta) {
    __shared__ float Y[1024], Z[1024], T[1024], S[32], M[32], sh_s;
    int g = blockIdx.x;
    int tid = threadIdx.x;

    if (tid < 32) {
        float s = 0.f;
        for (int pb = 0; pb < 64; ++pb) s += Spart[(size_t)(g*64 + pb)*32 + tid];
        S[tid] = s;
        M[tid] = s / (float)NTOT;
    }
    float rsum[4];
    #pragma unroll
    for (int i = 0; i < 4; ++i) {
        int e = tid + 256*i;
        float s = 0.f;
        for (int pb = 0; pb < 64; ++pb) s += Rpart[(size_t)(g*64 + pb)*1024 + e];
        rsum[i] = s;
    }
    __syncthreads();

    const float invN = 1.0f/(float)NTOT;
    #pragma unroll
    for (int i = 0; i < 4; ++i) {
        int e = tid + 256*i;
        int c = e >> 5, d = e & 31;
        float v = rsum[i] - S[c]*S[d]*invN;
        if (c == d) v += EPSV;
        T[e] = v;
    }
    __syncthreads();

    if (tid == 0) {
        float tr = 0.f;
        for (int c = 0; c < 32; ++c) tr += T[c*33];
        sh_s = tr / 32.0f;
    }
    __syncthreads();
    float sc = sh_s;
    float invs = 1.0f / sc;

    #pragma unroll
    for (int i = 0; i < 4; ++i) {
        int e = tid + 256*i;
        int c = e >> 5, d = e & 31;
        Y[e] = T[e] * invs;
        Z[e] = (c == d) ? 1.0f : 0.0f;
    }
    __syncthreads();

    for (int it = 0; it < 8; ++it) {
        float a[4];
        #pragma unroll
        for (int i = 0; i < 4; ++i) {
            int e = tid + 256*i;
            int c = e >> 5, d = e & 31;
            float s = 0.f;
            for (int k = 0; k < 32; ++k) s = fmaf(Z[c*32 + k], Y[k*32 + d], s);
            a[i] = ((c == d) ? 3.0f : 0.0f) - s;
        }
        __syncthreads();
        #pragma unroll
        for (int i = 0; i < 4; ++i) T[tid + 256*i] = a[i];
        __syncthreads();
        float yn[4], zn[4];
        #pragma unroll
        for (int i = 0; i < 4; ++i) {
            int e = tid + 256*i;
            int c = e >> 5, d = e & 31;
            float sy = 0.f, sz = 0.f;
            for (int k = 0; k < 32; ++k) {
                sy = fmaf(Y[c*32 + k], T[k*32 + d], sy);
                sz = fmaf(T[c*32 + k], Z[k*32 + d], sz);
            }
            yn[i] = 0.5f*sy; zn[i] = 0.5f*sz;
        }
        __syncthreads();
        #pragma unroll
        for (int i = 0; i < 4; ++i) { int e = tid + 256*i; Y[e] = yn[i]; Z[e] = zn[i]; }
        __syncthreads();
    }

    float wfac = rsqrtf(sc);   // sigma^{-1/2} = Z / sqrt(s)
    #pragma unroll
    for (int i = 0; i < 4; ++i) {
        int e = tid + 256*i;
        int c = e >> 5, d = e & 31;
        float wc = weight[g*GS + c];
        wmT[(size_t)g*1024 + d*32 + c] = Z[e]*wfac*wc;   // transposed + weight-folded
    }
    if (tid < 32) {
        int c = tid;
        float s = 0.f;
        for (int d = 0; d < 32; ++d) s = fmaf(Z[c*32 + d], M[d], s);
        beta[g*GS + c] = -s*wfac*weight[g*GS + c] + bias[g*GS + c];
    }
}

// ---------------------------------------------------------------------------
// Kernel 3: whiten. out[c] = sum_d wmT[d][c] * x[d] + beta[c].
// One thread per spatial position; wm/beta indices are wave-uniform -> s_load,
// inner loop is pure v_fmac(v, s, v). Memory-bound: 134 MB in + 134 MB out.
// ---------------------------------------------------------------------------
__global__ __launch_bounds__(256) void dbn_whiten(const float* __restrict__ x,
                                                  const float* __restrict__ wmT,
                                                  const float* __restrict__ beta,
                                                  float* __restrict__ out) {
    int bx = blockIdx.x;            // 0..4095
    int gb = bx >> 4;               // 0..255
    int chunk = bx & 15;
    int b = gb >> 3, g = gb & 7;
    size_t base = ((size_t)(b*NFEAT + g*GS))*HW + chunk*256 + threadIdx.x;
    const float* wg = wmT + (size_t)g*1024;
    const float* bg = beta + (size_t)g*GS;

    float v[32];
    #pragma unroll
    for (int d = 0; d < 32; ++d) v[d] = x[base + (size_t)d*HW];

    float acc[32];
    #pragma unroll
    for (int c = 0; c < 32; ++c) acc[c] = bg[c];

    #pragma unroll
    for (int d = 0; d < 32; ++d) {
        float vd = v[d];
        #pragma unroll
        for (int c = 0; c < 32; ++c) acc[c] = fmaf(wg[d*32 + c], vd, acc[c]);
    }

    #pragma unroll
    for (int c = 0; c < 32; ++c) out[base + (size_t)c*HW] = acc[c];
}

extern "C" void kernel_launch(void* const* d_in, const int* in_sizes, int n_in,
                              void* d_out, int out_size, void* d_ws, size_t ws_size,
                              hipStream_t stream) {
    const float* x      = (const float*)d_in[0];
    const float* weight = (const float*)d_in[1];
    const float* bias   = (const float*)d_in[2];
    float* out = (float*)d_out;
    float* ws  = (float*)d_ws;

    float* Rpart = ws;
    float* Spart = ws + SPART_OFF;
    float* wmT   = ws + WMT_OFF;
    float* beta  = ws + BETA_OFF;

    dbn_stats <<<512, 256, 0, stream>>>(x, Rpart, Spart);
    dbn_solver<<<NG, 256, 0, stream>>>(Rpart, Spart, weight, bias, wmT, beta);
    dbn_whiten<<<4096, 256, 0, stream>>>(x, wmT, beta, out);
}